// Round 7
// baseline (176.542 us; speedup 1.0000x reference)
//
#include <hip/hip_runtime.h>
#include <hip/hip_bf16.h>
#include <stdint.h>

typedef __attribute__((ext_vector_type(4)))  float  floatx4;
typedef __attribute__((ext_vector_type(16))) float  floatx16;
typedef __attribute__((ext_vector_type(8)))  short  short8;
typedef __attribute__((ext_vector_type(8)))  unsigned short ushortx8;
typedef __attribute__((ext_vector_type(4)))  unsigned short ushortx4;

#define B_  2
#define T_  2048
#define E_  1024
#define H_  16
#define D_  64
#define C_  128
#define NC_ 16
#define M_  4096   /* B*T */
#define EPS_ 1e-5f

__device__ __forceinline__ unsigned short f2b(float f) {
    union { float f; unsigned int u; } v; v.f = f;
    unsigned int r = v.u + 0x7fffu + ((v.u >> 16) & 1u);
    return (unsigned short)(r >> 16);
}
__device__ __forceinline__ float b2f(unsigned short b) {
    union { unsigned int u; float f; } v; v.u = ((unsigned int)b) << 16;
    return v.f;
}

// Swizzled fragment staging (R3/R4, generalized):
//   staging tile = 16 rows x 32 k (1 KB). lane i fetches global (row = i>>2,
//   kseg = (i&3) ^ ((i>>3)&3)) -> LDS slot i. Slot of (r,s) = sigma(r,s) =
//   r*4 + (s ^ ((r>>1)&3)). 4-lane clusters = one 64B line (coalesced);
//   any fragment read pattern over rows covers all 8 bank-quads per 8 lanes
//   (0 conflicts) — verified for both 16-row (16x16 MFMA) and 32-row (32x32
//   MFMA) read patterns.
__device__ __forceinline__ int stage_seg(int i) { return (i & 3) ^ ((i >> 3) & 3); }
__device__ __forceinline__ int sigma_slot(int r, int s) { return r * 4 + (s ^ ((r >> 1) & 3)); }
__device__ __forceinline__ int frag_slot(int lane) {   // 16x16 fragment read (m=lane&15, s=lane>>4)
    return sigma_slot(lane & 15, lane >> 4);
}

// ---------------- fused fp32 -> bf16 convert: x | Wq | Wk | Wv | Wo ----------------
__global__ __launch_bounds__(256) void convert_all(const float* __restrict__ x,
                                                   const float* __restrict__ Wq,
                                                   const float* __restrict__ Wk,
                                                   const float* __restrict__ Wv,
                                                   const float* __restrict__ Wo,
                                                   unsigned short* __restrict__ dst) {
    int i = (blockIdx.x * 256 + threadIdx.x) * 4;
    const float* s; int off;
    if (i < M_ * E_) { s = x; off = i; }
    else {
        int j = i - M_ * E_;
        int which = j >> 20;
        s = (which == 0) ? Wq : (which == 1) ? Wk : (which == 2) ? Wv : Wo;
        off = j & ((1 << 20) - 1);
    }
    float4 f = *(const float4*)(s + off);
    ushortx4 o;
    o[0] = f2b(f.x); o[1] = f2b(f.y); o[2] = f2b(f.z); o[3] = f2b(f.w);
    *(ushortx4*)(dst + i) = o;
}

// ---------------- QKV projection GEMM: C[4096,3072] = X @ W^T, phi on q,k ----------------
// 32x32x16 MFMA: halves LDS fragment bytes per FLOP vs 16x16x32 (R6 was
// LDS-pipe dominated: 17.5us LDS vs 10.3us MFMA). 2-wave blocks, wave-tile
// 64x64 (2x2 MFMA tiles), block 64x128, grid 24x64 = 1536 = 6 blocks/CU.
// Per k-step: 4 ds_read_b128 : 4 MFMA (32cyc each) -> latency-tolerant.
__global__ __launch_bounds__(128) void gemm_qkv(const unsigned short* __restrict__ A,
                                                const unsigned short* __restrict__ Bm,
                                                unsigned short* __restrict__ Cb) {
    const int N = 3 * E_, K = E_;
    __shared__ __align__(16) unsigned short at[8 * 512];    // 64 rows x 64 k
    __shared__ __align__(16) unsigned short bt[16 * 512];   // 128 cols x 64 k
    int tid = threadIdx.x;
    int w = tid >> 6, lane = tid & 63;
    int l31 = lane & 31, lh = lane >> 5;
    int srow = lane >> 2, sseg = stage_seg(lane);
    int row0 = blockIdx.y * 64, col0 = blockIdx.x * 128;
    floatx16 acc[2][2];
    for (int i = 0; i < 2; i++) for (int j = 0; j < 2; j++)
        for (int r = 0; r < 16; r++) acc[i][j][r] = 0.f;

    // precomputed fragment LDS offsets (within a kh group)
    int am[2], bn[2];
    for (int mi = 0; mi < 2; mi++) am[mi] = mi * 32 + l31;
    for (int nj = 0; nj < 2; nj++) bn[nj] = w * 64 + nj * 32 + l31;

    for (int k0 = 0; k0 < K; k0 += 64) {
        __syncthreads();
        for (int p = 0; p < 4; p++) {               // A: 8 tiles, 4 per wave
            int t = w * 4 + p;                      // kh = t>>2, rq = t&3
            const unsigned short* ga = A + (size_t)(row0 + (t & 3) * 16 + srow) * K + k0 + (t >> 2) * 32 + sseg * 8;
            __builtin_amdgcn_global_load_lds((const __attribute__((address_space(1))) unsigned int*)ga,
                (__attribute__((address_space(3))) unsigned int*)(at + t * 512), 16, 0, 0);
        }
        for (int p = 0; p < 8; p++) {               // B: 16 tiles, 8 per wave
            int u = w * 8 + p;                      // kh = u>>3, cq = u&7
            const unsigned short* gb = Bm + (size_t)(col0 + (u & 7) * 16 + srow) * K + k0 + (u >> 3) * 32 + sseg * 8;
            __builtin_amdgcn_global_load_lds((const __attribute__((address_space(1))) unsigned int*)gb,
                (__attribute__((address_space(3))) unsigned int*)(bt + u * 512), 16, 0, 0);
        }
        __syncthreads();
        for (int ks = 0; ks < 4; ks++) {            // 4 k-steps of 16
            int kh = ks >> 1;
            int s = (ks & 1) * 2 + lh;              // 8-elem segment within 32-k group
            short8 af[2], bf[2];
            for (int mi = 0; mi < 2; mi++) {
                int m = am[mi];
                af[mi] = *(const short8*)(at + (kh * 4 + (m >> 4)) * 512 + sigma_slot(m & 15, s) * 8);
            }
            for (int nj = 0; nj < 2; nj++) {
                int n = bn[nj];
                bf[nj] = *(const short8*)(bt + (kh * 8 + (n >> 4)) * 512 + sigma_slot(n & 15, s) * 8);
            }
            for (int mi = 0; mi < 2; mi++)
                for (int nj = 0; nj < 2; nj++)
                    acc[mi][nj] = __builtin_amdgcn_mfma_f32_32x32x16_bf16(af[mi], bf[nj], acc[mi][nj], 0, 0, 0);
        }
    }
    // epilogue: C/D layout col = lane&31, row = (reg&3) + 8*(reg>>2) + 4*(lane>>5)
    for (int mi = 0; mi < 2; mi++)
        for (int nj = 0; nj < 2; nj++) {
            int col = col0 + w * 64 + nj * 32 + l31;
            bool isphi = (col < 2 * E_);
            for (int reg = 0; reg < 16; reg++) {
                int row = row0 + mi * 32 + (reg & 3) + 8 * (reg >> 2) + 4 * lh;
                float v = acc[mi][nj][reg];
                if (isphi) v = (v > 0.f) ? (v + 1.f) : __expf(v);
                Cb[(size_t)row * N + col] = f2b(v);
            }
        }
}

// ---------------- Output GEMM: out[4096,1024] = attn @ Wo^T + bo (fp32 out) ----------------
// 64x64 tile, BK=64 -> grid 16x64 = 1024 blocks = 4/CU, LDS 16 KB.
__global__ __launch_bounds__(256) void gemm_out(const unsigned short* __restrict__ A,
                                                const unsigned short* __restrict__ Bm,
                                                const float* __restrict__ bias,
                                                float* __restrict__ Cf) {
    const int N = E_, K = E_;
    __shared__ __align__(16) unsigned short at[8 * 512];
    __shared__ __align__(16) unsigned short bt[8 * 512];
    int tid = threadIdx.x;
    int wave = tid >> 6, lane = tid & 63;
    int wr = wave >> 1, wc = wave & 1;
    int m = lane & 15, q = lane >> 4;
    int srow = lane >> 2, sseg = stage_seg(lane);
    int fs = frag_slot(lane);
    int row0 = blockIdx.y * 64, col0 = blockIdx.x * 64;
    floatx4 acc[2][2];
    for (int i = 0; i < 2; i++) for (int j = 0; j < 2; j++) acc[i][j] = floatx4{0.f, 0.f, 0.f, 0.f};

    for (int k0 = 0; k0 < K; k0 += 64) {
        __syncthreads();
        for (int p = 0; p < 2; p++) {
            int t = p * 4 + wave;
            int rt = t & 3, kh = t >> 2;
            const unsigned short* ga = A  + (size_t)(row0 + rt * 16 + srow) * K + k0 + kh * 32 + sseg * 8;
            const unsigned short* gb = Bm + (size_t)(col0 + rt * 16 + srow) * K + k0 + kh * 32 + sseg * 8;
            __builtin_amdgcn_global_load_lds((const __attribute__((address_space(1))) unsigned int*)ga,
                (__attribute__((address_space(3))) unsigned int*)(at + t * 512), 16, 0, 0);
            __builtin_amdgcn_global_load_lds((const __attribute__((address_space(1))) unsigned int*)gb,
                (__attribute__((address_space(3))) unsigned int*)(bt + t * 512), 16, 0, 0);
        }
        __syncthreads();
        for (int kh = 0; kh < 2; kh++) {
            short8 af[2], bfr[2];
            for (int mi = 0; mi < 2; mi++) af[mi]  = *(const short8*)(at + (kh * 4 + wr * 2 + mi) * 512 + fs * 8);
            for (int ci = 0; ci < 2; ci++) bfr[ci] = *(const short8*)(bt + (kh * 4 + wc * 2 + ci) * 512 + fs * 8);
            for (int mi = 0; mi < 2; mi++)
                for (int ci = 0; ci < 2; ci++)
                    acc[mi][ci] = __builtin_amdgcn_mfma_f32_16x16x32_bf16(af[mi], bfr[ci], acc[mi][ci], 0, 0, 0);
        }
    }
    int qrow = q * 4;
    for (int ci = 0; ci < 2; ci++) {
        int col = col0 + wc * 32 + ci * 16 + m;
        float bv = bias[col];
        for (int mi = 0; mi < 2; mi++)
            for (int r2 = 0; r2 < 4; r2++) {
                int row = row0 + wr * 32 + mi * 16 + qrow + r2;
                Cf[(size_t)row * N + col] = acc[mi][ci][r2] + bv;
            }
    }
}

// ---------------- per-chunk S_c = k_c^T v_c (64x64) and z_c (MFMA) ----------------
// A = K^T (m=d, k=t), B = V (k=t, n=e); extra n-col 64 = ones -> z_c.
__global__ __launch_bounds__(256) void chunk_sums(const unsigned short* __restrict__ qkv,
                                                  float* __restrict__ Sc, float* __restrict__ zc) {
    int c = blockIdx.x, h = blockIdx.y, bb = blockIdx.z;
    __shared__ __align__(16) unsigned short Kt[64 * 132];   // K^T: [d][t], stride 132 (conflict-free)
    __shared__ __align__(16) unsigned short Vt[80 * 132];   // V^T rows 0..63; row 64 = ones
    int tid = threadIdx.x;
    int lane = tid & 63, w = tid >> 6;
    size_t rowb = (size_t)bb * T_ + (size_t)c * C_;
    int kcol = E_ + h * D_, vcol = 2 * E_ + h * D_;

    for (int s = 0; s < 4; s++) {
        int off = s * 256 + tid;
        int r = off >> 3, seg = (off & 7) * 8;
        size_t g = (rowb + r) * 3072;
        ushortx8 k8 = *(const ushortx8*)(qkv + g + kcol + seg);
        ushortx8 v8 = *(const ushortx8*)(qkv + g + vcol + seg);
        for (int e = 0; e < 8; e++) {
            Kt[(seg + e) * 132 + r] = k8[e];
            Vt[(seg + e) * 132 + r] = v8[e];
        }
    }
    if (tid < 128) Vt[64 * 132 + tid] = 0x3f80;  // ones row (bf16 1.0)
    __syncthreads();

    floatx4 acc[5];
    for (int ni = 0; ni < 5; ni++) acc[ni] = floatx4{0.f, 0.f, 0.f, 0.f};
    int lm = lane & 15, lk = (lane >> 4) * 8;
    for (int k0 = 0; k0 < 128; k0 += 32) {
        short8 af = *(const short8*)(Kt + (w * 16 + lm) * 132 + k0 + lk);
        for (int ni = 0; ni < 5; ni++) {
            short8 bf = *(const short8*)(Vt + (ni * 16 + lm) * 132 + k0 + lk);
            acc[ni] = __builtin_amdgcn_mfma_f32_16x16x32_bf16(af, bf, acc[ni], 0, 0, 0);
        }
    }
    size_t base = ((size_t)(bb * H_ + h) * NC_ + c) * (size_t)(D_ * D_);
    int r0 = w * 16 + (lane >> 4) * 4;
    for (int ni = 0; ni < 4; ni++)
        for (int reg = 0; reg < 4; reg++)
            Sc[base + (size_t)(r0 + reg) * D_ + ni * 16 + lm] = acc[ni][reg];
    if (lm == 0) {
        size_t zb = ((size_t)(bb * H_ + h) * NC_ + c) * D_;
        for (int reg = 0; reg < 4; reg++) zc[zb + r0 + reg] = acc[4][reg];
    }
}

// ---------------- per-chunk attention (MFMA) ----------------
__global__ __launch_bounds__(256) void attn_kernel(const unsigned short* __restrict__ qkv,
                                                   const float* __restrict__ Sc,
                                                   const float* __restrict__ zc,
                                                   unsigned short* __restrict__ attn) {
    int c = blockIdx.x, h = blockIdx.y, bb = blockIdx.z;
    __shared__ __align__(16) unsigned short qs[128 * 68];   // Q row-major, stride 68
    __shared__ __align__(16) unsigned short ks[128 * 68];   // K row-major
    __shared__ __align__(16) unsigned short vt[64 * 132];   // V^T
    __shared__ __align__(16) unsigned short ovl[128 * 36];  // phase A: S_prev^T (stride 68); j-loop: P panel (stride 36)
    __shared__ float zsh[64];
    int tid = threadIdx.x;
    int lane = tid & 63, w = tid >> 6;
    int lm = lane & 15, lq = lane >> 4;
    size_t rowb = (size_t)bb * T_ + (size_t)c * C_;
    int qcol = h * D_, kcol = E_ + h * D_, vcol = 2 * E_ + h * D_;

    // ---- stage q, k (row-major) and v (transposed) ----
    for (int s = 0; s < 4; s++) {
        int off = s * 256 + tid;
        int r = off >> 3, seg = (off & 7) * 8;
        size_t g = (rowb + r) * 3072;
        ushortx8 q8 = *(const ushortx8*)(qkv + g + qcol + seg);
        ushortx8 k8 = *(const ushortx8*)(qkv + g + kcol + seg);
        ushortx8 v8 = *(const ushortx8*)(qkv + g + vcol + seg);
        *(ushortx8*)(qs + r * 68 + seg) = q8;
        *(ushortx8*)(ks + r * 68 + seg) = k8;
        for (int e = 0; e < 8; e++) vt[(seg + e) * 132 + r] = v8[e];
    }
    // ---- S_prev = sum_{j<c} Sc[j]  (store transposed bf16 into ovl, stride 68) ----
    {
        size_t scb = ((size_t)(bb * H_ + h) * NC_) * (size_t)(D_ * D_);
        int p = tid * 16;
        float a[16];
        for (int i = 0; i < 16; i++) a[i] = 0.f;
        for (int j = 0; j < c; j++) {
            const float* Sj = Sc + scb + (size_t)j * (D_ * D_) + p;
            for (int q = 0; q < 16; q += 4) {
                float4 f = *(const float4*)(Sj + q);
                a[q] += f.x; a[q + 1] += f.y; a[q + 2] += f.z; a[q + 3] += f.w;
            }
        }
        for (int i = 0; i < 16; i++) {
            int d = (p + i) >> 6, e = (p + i) & 63;
            ovl[e * 68 + d] = f2b(a[i]);
        }
    }
    // ---- z_prev (fp32) ----
    if (tid < 64) {
        size_t zb = ((size_t)(bb * H_ + h) * NC_) * D_;
        float zr = 0.f;
        for (int j = 0; j < c; j++) zr += zc[zb + (size_t)j * D_ + tid];
        zsh[tid] = zr;
    }
    __syncthreads();

    // ---- phase A: acc = Q @ S_prev  (wave w -> rows [w*32, w*32+32)) ----
    floatx4 acc[2][4];
    for (int mi = 0; mi < 2; mi++) for (int ni = 0; ni < 4; ni++) acc[mi][ni] = floatx4{0.f, 0.f, 0.f, 0.f};
    for (int k0 = 0; k0 < 64; k0 += 32) {
        short8 aq[2];
        for (int mi = 0; mi < 2; mi++)
            aq[mi] = *(const short8*)(qs + (w * 32 + mi * 16 + lm) * 68 + k0 + lq * 8);
        for (int ni = 0; ni < 4; ni++) {
            short8 bs = *(const short8*)(ovl + (ni * 16 + lm) * 68 + k0 + lq * 8);
            for (int mi = 0; mi < 2; mi++)
                acc[mi][ni] = __builtin_amdgcn_mfma_f32_16x16x32_bf16(aq[mi], bs, acc[mi][ni], 0, 0, 0);
        }
    }
    // ---- dsum init: q . z_prev per output row (C-layout rows), fp32 ----
    float dsum[2][4];
    {
        int d0 = lm * 4;
        float4 z4 = *(const float4*)(zsh + d0);
        for (int mi = 0; mi < 2; mi++)
            for (int reg = 0; reg < 4; reg++) {
                int row = w * 32 + mi * 16 + lq * 4 + reg;
                ushortx4 q4 = *(const ushortx4*)(qs + row * 68 + d0);
                dsum[mi][reg] = b2f(q4[0]) * z4.x + b2f(q4[1]) * z4.y + b2f(q4[2]) * z4.z + b2f(q4[3]) * z4.w;
            }
    }
    __syncthreads();  // all waves done reading S_prev^T from ovl before P writes

    // ---- intra-chunk j-loop: wave w only needs j-tiles jt <= w (causality) ----
    for (int jt = 0; jt <= w; jt++) {
        floatx4 pa[2][2];
        for (int mi = 0; mi < 2; mi++) for (int ct = 0; ct < 2; ct++) pa[mi][ct] = floatx4{0.f, 0.f, 0.f, 0.f};
        for (int k0 = 0; k0 < 64; k0 += 32) {
            short8 aq[2];
            for (int mi = 0; mi < 2; mi++)
                aq[mi] = *(const short8*)(qs + (w * 32 + mi * 16 + lm) * 68 + k0 + lq * 8);
            for (int ct = 0; ct < 2; ct++) {
                short8 bk = *(const short8*)(ks + (jt * 32 + ct * 16 + lm) * 68 + k0 + lq * 8);
                for (int mi = 0; mi < 2; mi++)
                    pa[mi][ct] = __builtin_amdgcn_mfma_f32_16x16x32_bf16(aq[mi], bk, pa[mi][ct], 0, 0, 0);
            }
        }
        bool diag = (jt == w);
        for (int mi = 0; mi < 2; mi++)
            for (int ct = 0; ct < 2; ct++)
                for (int reg = 0; reg < 4; reg++) {
                    int il = mi * 16 + lq * 4 + reg;   // row within wave's 32
                    int jl = ct * 16 + lm;             // col within j-tile's 32
                    float v = pa[mi][ct][reg];
                    if (diag && jl > il) v = 0.f;
                    dsum[mi][reg] += v;
                    ovl[(w * 32 + il) * 36 + jl] = f2b(v);
                }
        // PV: P (A-layout from own rows of ovl) x V^T slice, K=32
        short8 ap[2];
        for (int mi = 0; mi < 2; mi++)
            ap[mi] = *(const short8*)(ovl + (w * 32 + mi * 16 + lm) * 36 + lq * 8);
        for (int ni = 0; ni < 4; ni++) {
            short8 bv = *(const short8*)(vt + (ni * 16 + lm) * 132 + jt * 32 + lq * 8);
            for (int mi = 0; mi < 2; mi++)
                acc[mi][ni] = __builtin_amdgcn_mfma_f32_16x16x32_bf16(ap[mi], bv, acc[mi][ni], 0, 0, 0);
        }
    }

    // ---- reduce dsum across the 16-lane col group ----
    for (int off = 1; off < 16; off <<= 1)
        for (int mi = 0; mi < 2; mi++)
            for (int reg = 0; reg < 4; reg++)
                dsum[mi][reg] += __shfl_xor(dsum[mi][reg], off);

    // ---- epilogue: out = num / den ----
    for (int mi = 0; mi < 2; mi++)
        for (int reg = 0; reg < 4; reg++) {
            float inv = 1.f / (dsum[mi][reg] + EPS_);
            int row = w * 32 + mi * 16 + lq * 4 + reg;
            for (int ni = 0; ni < 4; ni++)
                attn[(rowb + row) * E_ + h * D_ + ni * 16 + lm] = f2b(acc[mi][ni][reg] * inv);
        }
}

extern "C" void kernel_launch(void* const* d_in, const int* in_sizes, int n_in,
                              void* d_out, int out_size, void* d_ws, size_t ws_size,
                              hipStream_t stream) {
    const float* x  = (const float*)d_in[0];
    const float* Wq = (const float*)d_in[1];
    const float* Wk = (const float*)d_in[2];
    const float* Wv = (const float*)d_in[3];
    const float* Wo = (const float*)d_in[4];
    const float* bo = (const float*)d_in[5];
    float* out = (float*)d_out;

    const size_t MB = 1024 * 1024;
    uint8_t* ws = (uint8_t*)d_ws;
    unsigned short* xb    = (unsigned short*)(ws + 0);        // 8 MB, reused as attn buffer
    unsigned short* wb    = (unsigned short*)(ws + 8 * MB);   // 8 MB (Wq|Wk|Wv|Wo bf16, contiguous with xb)
    unsigned short* wob   = wb + 3 * E_ * E_;
    unsigned short* qkvb  = (unsigned short*)(ws + 16 * MB);  // 24 MB
    float* Sc = (float*)(ws + 40 * MB);                       // 8 MB
    float* zc = (float*)(ws + 48 * MB);                       // 128 KB
    unsigned short* attnb = xb;

    convert_all<<<(M_ * E_ + 4 * E_ * E_) / 1024, 256, 0, stream>>>(x, Wq, Wk, Wv, Wo, xb);

    gemm_qkv<<<dim3(24, 64), 128, 0, stream>>>(xb, wb, qkvb);
    chunk_sums<<<dim3(NC_, H_, B_), 256, 0, stream>>>(qkvb, Sc, zc);
    attn_kernel<<<dim3(NC_, H_, B_), 256, 0, stream>>>(qkvb, Sc, zc, attnb);
    gemm_out<<<dim3(16, 64), 256, 0, stream>>>(attnb, wob, bo, out);
}

// Round 8
// 174.704 us; speedup vs baseline: 1.0105x; 1.0105x over previous
//
#include <hip/hip_runtime.h>
#include <hip/hip_bf16.h>
#include <stdint.h>

typedef __attribute__((ext_vector_type(4)))  float  floatx4;
typedef __attribute__((ext_vector_type(8)))  short  short8;
typedef __attribute__((ext_vector_type(8)))  unsigned short ushortx8;
typedef __attribute__((ext_vector_type(4)))  unsigned short ushortx4;

#define B_  2
#define T_  2048
#define E_  1024
#define H_  16
#define D_  64
#define C_  128
#define NC_ 16
#define M_  4096   /* B*T */
#define EPS_ 1e-5f

__device__ __forceinline__ unsigned short f2b(float f) {
    union { float f; unsigned int u; } v; v.f = f;
    unsigned int r = v.u + 0x7fffu + ((v.u >> 16) & 1u);
    return (unsigned short)(r >> 16);
}
__device__ __forceinline__ float b2f(unsigned short b) {
    union { unsigned int u; float f; } v; v.u = ((unsigned int)b) << 16;
    return v.f;
}

// Swizzled fragment staging (R3/R4; R7 errata):
//   staging tile = 16 rows x 32 k (1 KB). lane i fetches global (row = i>>2,
//   kseg = (i&3) ^ ((i>>3)&3)) -> LDS slot i (16B). Fragment read: lane l
//   reads slot sigma(l&15, l>>4) = m*4 + (q ^ ((m>>1)&3)).
//   EMPIRICAL RULE (R7 post-mortem): the ds_read tile BASE must be
//   wave-uniform — per-lane tile selection (spanning 2 tiles in one
//   instruction) re-creates ~4 cyc/read conflict counts even when bank-quad
//   math says clean. All reads below use wave-uniform tile bases.
__device__ __forceinline__ int stage_seg(int i) { return (i & 3) ^ ((i >> 3) & 3); }
__device__ __forceinline__ int frag_slot(int lane) {
    int m = lane & 15, q = lane >> 4;
    return m * 4 + (q ^ ((m >> 1) & 3));
}

// ---------------- fused fp32 -> bf16 convert: x | Wq | Wk | Wv | Wo ----------------
__global__ __launch_bounds__(256) void convert_all(const float* __restrict__ x,
                                                   const float* __restrict__ Wq,
                                                   const float* __restrict__ Wk,
                                                   const float* __restrict__ Wv,
                                                   const float* __restrict__ Wo,
                                                   unsigned short* __restrict__ dst) {
    int i = (blockIdx.x * 256 + threadIdx.x) * 4;
    const float* s; int off;
    if (i < M_ * E_) { s = x; off = i; }
    else {
        int j = i - M_ * E_;
        int which = j >> 20;
        s = (which == 0) ? Wq : (which == 1) ? Wk : (which == 2) ? Wv : Wo;
        off = j & ((1 << 20) - 1);
    }
    float4 f = *(const float4*)(s + off);
    ushortx4 o;
    o[0] = f2b(f.x); o[1] = f2b(f.y); o[2] = f2b(f.z); o[3] = f2b(f.w);
    *(ushortx4*)(dst + i) = o;
}

// ---------------- QKV projection GEMM: C[4096,3072] = X @ W^T, phi on q,k ----------------
// 2-wave block, 64x128 tile, BK=64, wave-tile 64x64 (4x4 16x16x32 MFMA).
// Per wave per kh: 8 ds_read_b128 : 16 MFMA (2:1 — R6 was 6:8) -> LDS bytes
// per FLOP halved while keeping the proven wave-uniform-base sigma reads.
// Grid 24x64 = 1536 = 6 blocks/CU (R6 co-residency), LDS 24 KB.
__global__ __launch_bounds__(128) void gemm_qkv(const unsigned short* __restrict__ A,
                                                const unsigned short* __restrict__ Bm,
                                                unsigned short* __restrict__ Cb) {
    const int N = 3 * E_, K = E_;
    __shared__ __align__(16) unsigned short at[8 * 512];    // 64 rows x 64 k
    __shared__ __align__(16) unsigned short bt[16 * 512];   // 128 cols x 64 k
    int tid = threadIdx.x;
    int w = tid >> 6, lane = tid & 63;
    int m = lane & 15, q = lane >> 4;
    int srow = lane >> 2, sseg = stage_seg(lane);
    int fs = frag_slot(lane);
    int row0 = blockIdx.y * 64, col0 = blockIdx.x * 128;
    floatx4 acc[4][4];
    for (int i = 0; i < 4; i++) for (int j = 0; j < 4; j++) acc[i][j] = floatx4{0.f, 0.f, 0.f, 0.f};

    for (int k0 = 0; k0 < K; k0 += 64) {
        __syncthreads();
        for (int p = 0; p < 4; p++) {               // A: 8 tiles, 4 per wave
            int t = w * 4 + p;                      // rq = t&3, kh = t>>2
            const unsigned short* ga = A + (size_t)(row0 + (t & 3) * 16 + srow) * K + k0 + (t >> 2) * 32 + sseg * 8;
            __builtin_amdgcn_global_load_lds((const __attribute__((address_space(1))) unsigned int*)ga,
                (__attribute__((address_space(3))) unsigned int*)(at + t * 512), 16, 0, 0);
        }
        for (int p = 0; p < 8; p++) {               // B: 16 tiles, 8 per wave
            int u = w * 8 + p;                      // cq = u&7, kh = u>>3
            const unsigned short* gb = Bm + (size_t)(col0 + (u & 7) * 16 + srow) * K + k0 + (u >> 3) * 32 + sseg * 8;
            __builtin_amdgcn_global_load_lds((const __attribute__((address_space(1))) unsigned int*)gb,
                (__attribute__((address_space(3))) unsigned int*)(bt + u * 512), 16, 0, 0);
        }
        __syncthreads();
        for (int kh = 0; kh < 2; kh++) {
            short8 af[4], bf[4];
            for (int mi = 0; mi < 4; mi++) af[mi] = *(const short8*)(at + (kh * 4 + mi) * 512 + fs * 8);
            for (int ni = 0; ni < 4; ni++) bf[ni] = *(const short8*)(bt + (kh * 8 + w * 4 + ni) * 512 + fs * 8);
            for (int mi = 0; mi < 4; mi++)
                for (int ni = 0; ni < 4; ni++)
                    acc[mi][ni] = __builtin_amdgcn_mfma_f32_16x16x32_bf16(af[mi], bf[ni], acc[mi][ni], 0, 0, 0);
        }
    }
    int qrow = q * 4;
    for (int mi = 0; mi < 4; mi++) for (int ni = 0; ni < 4; ni++) {
        int col = col0 + w * 64 + ni * 16 + m;
        bool isphi = (col < 2 * E_);
        for (int r2 = 0; r2 < 4; r2++) {
            int row = row0 + mi * 16 + qrow + r2;
            float v = acc[mi][ni][r2];
            if (isphi) v = (v > 0.f) ? (v + 1.f) : __expf(v);
            Cb[(size_t)row * N + col] = f2b(v);
        }
    }
}

// ---------------- Output GEMM: out[4096,1024] = attn @ Wo^T + bo (fp32 out) ----------------
// 2-wave block, 64x64 tile, BK=64, wave-tile 64x32 (4x2 MFMA). Grid 16x64 =
// 1024 = 4/CU, LDS 16 KB. Per wave per kh: 6 reads : 8 MFMA.
__global__ __launch_bounds__(128) void gemm_out(const unsigned short* __restrict__ A,
                                                const unsigned short* __restrict__ Bm,
                                                const float* __restrict__ bias,
                                                float* __restrict__ Cf) {
    const int N = E_, K = E_;
    __shared__ __align__(16) unsigned short at[8 * 512];
    __shared__ __align__(16) unsigned short bt[8 * 512];
    int tid = threadIdx.x;
    int w = tid >> 6, lane = tid & 63;
    int m = lane & 15, q = lane >> 4;
    int srow = lane >> 2, sseg = stage_seg(lane);
    int fs = frag_slot(lane);
    int row0 = blockIdx.y * 64, col0 = blockIdx.x * 64;
    floatx4 acc[4][2];
    for (int i = 0; i < 4; i++) for (int j = 0; j < 2; j++) acc[i][j] = floatx4{0.f, 0.f, 0.f, 0.f};

    for (int k0 = 0; k0 < K; k0 += 64) {
        __syncthreads();
        for (int p = 0; p < 4; p++) {
            int t = w * 4 + p;                      // rq = t&3, kh = t>>2
            const unsigned short* ga = A  + (size_t)(row0 + (t & 3) * 16 + srow) * K + k0 + (t >> 2) * 32 + sseg * 8;
            const unsigned short* gb = Bm + (size_t)(col0 + (t & 3) * 16 + srow) * K + k0 + (t >> 2) * 32 + sseg * 8;
            __builtin_amdgcn_global_load_lds((const __attribute__((address_space(1))) unsigned int*)ga,
                (__attribute__((address_space(3))) unsigned int*)(at + t * 512), 16, 0, 0);
            __builtin_amdgcn_global_load_lds((const __attribute__((address_space(1))) unsigned int*)gb,
                (__attribute__((address_space(3))) unsigned int*)(bt + t * 512), 16, 0, 0);
        }
        __syncthreads();
        for (int kh = 0; kh < 2; kh++) {
            short8 af[4], bf[2];
            for (int mi = 0; mi < 4; mi++) af[mi] = *(const short8*)(at + (kh * 4 + mi) * 512 + fs * 8);
            for (int ci = 0; ci < 2; ci++) bf[ci] = *(const short8*)(bt + (kh * 4 + w * 2 + ci) * 512 + fs * 8);
            for (int mi = 0; mi < 4; mi++)
                for (int ci = 0; ci < 2; ci++)
                    acc[mi][ci] = __builtin_amdgcn_mfma_f32_16x16x32_bf16(af[mi], bf[ci], acc[mi][ci], 0, 0, 0);
        }
    }
    int qrow = q * 4;
    for (int ci = 0; ci < 2; ci++) {
        int col = col0 + w * 32 + ci * 16 + m;
        float bv = bias[col];
        for (int mi = 0; mi < 4; mi++)
            for (int r2 = 0; r2 < 4; r2++) {
                int row = row0 + mi * 16 + qrow + r2;
                Cf[(size_t)row * N + col] = acc[mi][ci][r2] + bv;
            }
    }
}

// ---------------- per-chunk S_c = k_c^T v_c (64x64) and z_c (MFMA) ----------------
// A = K^T (m=d, k=t), B = V (k=t, n=e); extra n-col 64 = ones -> z_c.
__global__ __launch_bounds__(256) void chunk_sums(const unsigned short* __restrict__ qkv,
                                                  float* __restrict__ Sc, float* __restrict__ zc) {
    int c = blockIdx.x, h = blockIdx.y, bb = blockIdx.z;
    __shared__ __align__(16) unsigned short Kt[64 * 132];   // K^T: [d][t], stride 132 (conflict-free)
    __shared__ __align__(16) unsigned short Vt[80 * 132];   // V^T rows 0..63; row 64 = ones
    int tid = threadIdx.x;
    int lane = tid & 63, w = tid >> 6;
    size_t rowb = (size_t)bb * T_ + (size_t)c * C_;
    int kcol = E_ + h * D_, vcol = 2 * E_ + h * D_;

    for (int s = 0; s < 4; s++) {
        int off = s * 256 + tid;
        int r = off >> 3, seg = (off & 7) * 8;
        size_t g = (rowb + r) * 3072;
        ushortx8 k8 = *(const ushortx8*)(qkv + g + kcol + seg);
        ushortx8 v8 = *(const ushortx8*)(qkv + g + vcol + seg);
        for (int e = 0; e < 8; e++) {
            Kt[(seg + e) * 132 + r] = k8[e];
            Vt[(seg + e) * 132 + r] = v8[e];
        }
    }
    if (tid < 128) Vt[64 * 132 + tid] = 0x3f80;  // ones row (bf16 1.0)
    __syncthreads();

    floatx4 acc[5];
    for (int ni = 0; ni < 5; ni++) acc[ni] = floatx4{0.f, 0.f, 0.f, 0.f};
    int lm = lane & 15, lk = (lane >> 4) * 8;
    for (int k0 = 0; k0 < 128; k0 += 32) {
        short8 af = *(const short8*)(Kt + (w * 16 + lm) * 132 + k0 + lk);
        for (int ni = 0; ni < 5; ni++) {
            short8 bf = *(const short8*)(Vt + (ni * 16 + lm) * 132 + k0 + lk);
            acc[ni] = __builtin_amdgcn_mfma_f32_16x16x32_bf16(af, bf, acc[ni], 0, 0, 0);
        }
    }
    size_t base = ((size_t)(bb * H_ + h) * NC_ + c) * (size_t)(D_ * D_);
    int r0 = w * 16 + (lane >> 4) * 4;
    for (int ni = 0; ni < 4; ni++)
        for (int reg = 0; reg < 4; reg++)
            Sc[base + (size_t)(r0 + reg) * D_ + ni * 16 + lm] = acc[ni][reg];
    if (lm == 0) {
        size_t zb = ((size_t)(bb * H_ + h) * NC_ + c) * D_;
        for (int reg = 0; reg < 4; reg++) zc[zb + r0 + reg] = acc[4][reg];
    }
}

// ---------------- per-chunk attention (MFMA) ----------------
__global__ __launch_bounds__(256) void attn_kernel(const unsigned short* __restrict__ qkv,
                                                   const float* __restrict__ Sc,
                                                   const float* __restrict__ zc,
                                                   unsigned short* __restrict__ attn) {
    int c = blockIdx.x, h = blockIdx.y, bb = blockIdx.z;
    __shared__ __align__(16) unsigned short qs[128 * 68];   // Q row-major, stride 68
    __shared__ __align__(16) unsigned short ks[128 * 68];   // K row-major
    __shared__ __align__(16) unsigned short vt[64 * 132];   // V^T
    __shared__ __align__(16) unsigned short ovl[128 * 36];  // phase A: S_prev^T (stride 68); j-loop: P panel (stride 36)
    __shared__ float zsh[64];
    int tid = threadIdx.x;
    int lane = tid & 63, w = tid >> 6;
    int lm = lane & 15, lq = lane >> 4;
    size_t rowb = (size_t)bb * T_ + (size_t)c * C_;
    int qcol = h * D_, kcol = E_ + h * D_, vcol = 2 * E_ + h * D_;

    // ---- stage q, k (row-major) and v (transposed) ----
    for (int s = 0; s < 4; s++) {
        int off = s * 256 + tid;
        int r = off >> 3, seg = (off & 7) * 8;
        size_t g = (rowb + r) * 3072;
        ushortx8 q8 = *(const ushortx8*)(qkv + g + qcol + seg);
        ushortx8 k8 = *(const ushortx8*)(qkv + g + kcol + seg);
        ushortx8 v8 = *(const ushortx8*)(qkv + g + vcol + seg);
        *(ushortx8*)(qs + r * 68 + seg) = q8;
        *(ushortx8*)(ks + r * 68 + seg) = k8;
        for (int e = 0; e < 8; e++) vt[(seg + e) * 132 + r] = v8[e];
    }
    // ---- S_prev = sum_{j<c} Sc[j]  (store transposed bf16 into ovl, stride 68) ----
    {
        size_t scb = ((size_t)(bb * H_ + h) * NC_) * (size_t)(D_ * D_);
        int p = tid * 16;
        float a[16];
        for (int i = 0; i < 16; i++) a[i] = 0.f;
        for (int j = 0; j < c; j++) {
            const float* Sj = Sc + scb + (size_t)j * (D_ * D_) + p;
            for (int q = 0; q < 16; q += 4) {
                float4 f = *(const float4*)(Sj + q);
                a[q] += f.x; a[q + 1] += f.y; a[q + 2] += f.z; a[q + 3] += f.w;
            }
        }
        for (int i = 0; i < 16; i++) {
            int d = (p + i) >> 6, e = (p + i) & 63;
            ovl[e * 68 + d] = f2b(a[i]);
        }
    }
    // ---- z_prev (fp32) ----
    if (tid < 64) {
        size_t zb = ((size_t)(bb * H_ + h) * NC_) * D_;
        float zr = 0.f;
        for (int j = 0; j < c; j++) zr += zc[zb + (size_t)j * D_ + tid];
        zsh[tid] = zr;
    }
    __syncthreads();

    // ---- phase A: acc = Q @ S_prev  (wave w -> rows [w*32, w*32+32)) ----
    floatx4 acc[2][4];
    for (int mi = 0; mi < 2; mi++) for (int ni = 0; ni < 4; ni++) acc[mi][ni] = floatx4{0.f, 0.f, 0.f, 0.f};
    for (int k0 = 0; k0 < 64; k0 += 32) {
        short8 aq[2];
        for (int mi = 0; mi < 2; mi++)
            aq[mi] = *(const short8*)(qs + (w * 32 + mi * 16 + lm) * 68 + k0 + lq * 8);
        for (int ni = 0; ni < 4; ni++) {
            short8 bs = *(const short8*)(ovl + (ni * 16 + lm) * 68 + k0 + lq * 8);
            for (int mi = 0; mi < 2; mi++)
                acc[mi][ni] = __builtin_amdgcn_mfma_f32_16x16x32_bf16(aq[mi], bs, acc[mi][ni], 0, 0, 0);
        }
    }
    // ---- dsum init: q . z_prev per output row (C-layout rows), fp32 ----
    float dsum[2][4];
    {
        int d0 = lm * 4;
        float4 z4 = *(const float4*)(zsh + d0);
        for (int mi = 0; mi < 2; mi++)
            for (int reg = 0; reg < 4; reg++) {
                int row = w * 32 + mi * 16 + lq * 4 + reg;
                ushortx4 q4 = *(const ushortx4*)(qs + row * 68 + d0);
                dsum[mi][reg] = b2f(q4[0]) * z4.x + b2f(q4[1]) * z4.y + b2f(q4[2]) * z4.z + b2f(q4[3]) * z4.w;
            }
    }
    __syncthreads();  // all waves done reading S_prev^T from ovl before P writes

    // ---- intra-chunk j-loop: wave w only needs j-tiles jt <= w (causality) ----
    for (int jt = 0; jt <= w; jt++) {
        floatx4 pa[2][2];
        for (int mi = 0; mi < 2; mi++) for (int ct = 0; ct < 2; ct++) pa[mi][ct] = floatx4{0.f, 0.f, 0.f, 0.f};
        for (int k0 = 0; k0 < 64; k0 += 32) {
            short8 aq[2];
            for (int mi = 0; mi < 2; mi++)
                aq[mi] = *(const short8*)(qs + (w * 32 + mi * 16 + lm) * 68 + k0 + lq * 8);
            for (int ct = 0; ct < 2; ct++) {
                short8 bk = *(const short8*)(ks + (jt * 32 + ct * 16 + lm) * 68 + k0 + lq * 8);
                for (int mi = 0; mi < 2; mi++)
                    pa[mi][ct] = __builtin_amdgcn_mfma_f32_16x16x32_bf16(aq[mi], bk, pa[mi][ct], 0, 0, 0);
            }
        }
        bool diag = (jt == w);
        for (int mi = 0; mi < 2; mi++)
            for (int ct = 0; ct < 2; ct++)
                for (int reg = 0; reg < 4; reg++) {
                    int il = mi * 16 + lq * 4 + reg;   // row within wave's 32
                    int jl = ct * 16 + lm;             // col within j-tile's 32
                    float v = pa[mi][ct][reg];
                    if (diag && jl > il) v = 0.f;
                    dsum[mi][reg] += v;
                    ovl[(w * 32 + il) * 36 + jl] = f2b(v);
                }
        // PV: P (A-layout from own rows of ovl) x V^T slice, K=32
        short8 ap[2];
        for (int mi = 0; mi < 2; mi++)
            ap[mi] = *(const short8*)(ovl + (w * 32 + mi * 16 + lm) * 36 + lq * 8);
        for (int ni = 0; ni < 4; ni++) {
            short8 bv = *(const short8*)(vt + (ni * 16 + lm) * 132 + jt * 32 + lq * 8);
            for (int mi = 0; mi < 2; mi++)
                acc[mi][ni] = __builtin_amdgcn_mfma_f32_16x16x32_bf16(ap[mi], bv, acc[mi][ni], 0, 0, 0);
        }
    }

    // ---- reduce dsum across the 16-lane col group ----
    for (int off = 1; off < 16; off <<= 1)
        for (int mi = 0; mi < 2; mi++)
            for (int reg = 0; reg < 4; reg++)
                dsum[mi][reg] += __shfl_xor(dsum[mi][reg], off);

    // ---- epilogue: out = num / den ----
    for (int mi = 0; mi < 2; mi++)
        for (int reg = 0; reg < 4; reg++) {
            float inv = 1.f / (dsum[mi][reg] + EPS_);
            int row = w * 32 + mi * 16 + lq * 4 + reg;
            for (int ni = 0; ni < 4; ni++)
                attn[(rowb + row) * E_ + h * D_ + ni * 16 + lm] = f2b(acc[mi][ni][reg] * inv);
        }
}

extern "C" void kernel_launch(void* const* d_in, const int* in_sizes, int n_in,
                              void* d_out, int out_size, void* d_ws, size_t ws_size,
                              hipStream_t stream) {
    const float* x  = (const float*)d_in[0];
    const float* Wq = (const float*)d_in[1];
    const float* Wk = (const float*)d_in[2];
    const float* Wv = (const float*)d_in[3];
    const float* Wo = (const float*)d_in[4];
    const float* bo = (const float*)d_in[5];
    float* out = (float*)d_out;

    const size_t MB = 1024 * 1024;
    uint8_t* ws = (uint8_t*)d_ws;
    unsigned short* xb    = (unsigned short*)(ws + 0);        // 8 MB, reused as attn buffer
    unsigned short* wb    = (unsigned short*)(ws + 8 * MB);   // 8 MB (Wq|Wk|Wv|Wo bf16, contiguous with xb)
    unsigned short* wob   = wb + 3 * E_ * E_;
    unsigned short* qkvb  = (unsigned short*)(ws + 16 * MB);  // 24 MB
    float* Sc = (float*)(ws + 40 * MB);                       // 8 MB
    float* zc = (float*)(ws + 48 * MB);                       // 128 KB
    unsigned short* attnb = xb;

    convert_all<<<(M_ * E_ + 4 * E_ * E_) / 1024, 256, 0, stream>>>(x, Wq, Wk, Wv, Wo, xb);

    gemm_qkv<<<dim3(24, 64), 128, 0, stream>>>(xb, wb, qkvb);
    chunk_sums<<<dim3(NC_, H_, B_), 256, 0, stream>>>(qkvb, Sc, zc);
    attn_kernel<<<dim3(NC_, H_, B_), 256, 0, stream>>>(qkvb, Sc, zc, attnb);
    gemm_out<<<dim3(16, 64), 128, 0, stream>>>(attnb, wob, bo, out);
}